// Round 8
// baseline (4538.231 us; speedup 1.0000x reference)
//
#include <hip/hip_runtime.h>
#include <hip/hip_bf16.h>
#include <stdint.h>

// ---------------------------------------------------------------------------
// DeepLSTMDecoderLayer R8:
//  - GEMMs: 128x128 tile, BK=32, global_load_lds width-16 staging (m97-style)
//  - flash attention 64x64 (validated R1/R2)
//  - LSTM scan (R7 base: sentinel data-poll, split-K, 1 barrier/phase) +
//    ANTI-PHASE batch pipelining: batches 0-7 (A) and 8-15 (B) are
//    independent recurrences processed in alternating half-slots; each
//    group's L3 propagate+detect hides under the other group's compute.
//    MFMA rows 8-15 duplicate rows 0-7 (results unused). Gate partials in
//    padded LDS [8][132] (conflict-free writes, float4 reads).
// ws layout (MiB offsets), peak ~234 MiB: unchanged from R7.
// ---------------------------------------------------------------------------

typedef unsigned short u16;
typedef unsigned int u32;
typedef unsigned long long u64;
typedef __bf16 bf16x8 __attribute__((ext_vector_type(8)));
typedef float f32x4 __attribute__((ext_vector_type(4)));
typedef int int32x4 __attribute__((ext_vector_type(4)));
typedef unsigned long long u64x2 __attribute__((ext_vector_type(2)));

#define DEV static __device__ __forceinline__

DEV u16 f2bf(float x) {
  u32 u = __builtin_bit_cast(u32, x);
  u += 0x7FFF + ((u >> 16) & 1);  // round-to-nearest-even
  return (u16)(u >> 16);
}

DEV bf16x8 ldfrag(const void* p) {
  int32x4 v = *(const int32x4*)p;
  return __builtin_bit_cast(bf16x8, v);
}

DEV bf16x8 mkfrag(u64 lo, u64 hi) {
  u64x2 v;
  v.x = lo;
  v.y = hi;
  return __builtin_bit_cast(bf16x8, v);
}

DEV f32x4 mfma_bf16(bf16x8 a, bf16x8 b, f32x4 c) {
  return __builtin_amdgcn_mfma_f32_16x16x32_bf16(a, b, c, 0, 0, 0);
}

// async global->LDS, 16B per lane; LDS dest is wave-uniform base (+lane*16 HW)
DEV void load_lds16(const u16* g, u16* l) {
  __builtin_amdgcn_global_load_lds(
      (__attribute__((address_space(1))) void*)(uintptr_t)g,
      (__attribute__((address_space(3))) void*)(uintptr_t)l, 16, 0, 0);
}

// ---------------- conversion kernels ----------------

__global__ __launch_bounds__(256) void cvt_bf16_kernel(u16* __restrict__ out,
                                                       const float* __restrict__ in,
                                                       int n4) {
  int i = blockIdx.x * 256 + threadIdx.x;
  if (i >= n4) return;
  float4 v = ((const float4*)in)[i];
  ushort4 s;
  s.x = f2bf(v.x); s.y = f2bf(v.y); s.z = f2bf(v.z); s.w = f2bf(v.w);
  ((ushort4*)out)[i] = s;
}

// x[8192][1024] f32 -> xcb[r][0..1023] with row stride 2048
__global__ __launch_bounds__(256) void cvt_x_kernel(u16* __restrict__ out,
                                                    const float* __restrict__ in) {
  int i = blockIdx.x * 256 + threadIdx.x;  // 8192*256 float4 groups
  int r = i >> 8, cg4 = i & 255;
  float4 v = ((const float4*)in)[i];
  ushort4 s;
  s.x = f2bf(v.x); s.y = f2bf(v.y); s.z = f2bf(v.z); s.w = f2bf(v.w);
  *(ushort4*)(out + (size_t)r * 2048 + cg4 * 4) = s;
}

// out[n*K + k] = in[(k+koff)*N + n] * scale   (tiled transpose-convert)
__global__ __launch_bounds__(256) void convt_kernel(u16* __restrict__ out,
                                                    const float* __restrict__ in,
                                                    int K, int N, int koff, float scale) {
  __shared__ float tile[32][33];
  const int tid = threadIdx.x;
  const int n0 = blockIdx.x * 32, k0 = blockIdx.y * 32;
  const int c = tid & 31, r = tid >> 5;
#pragma unroll
  for (int i = 0; i < 4; ++i)
    tile[r + i * 8][c] = in[(size_t)(k0 + r + i * 8 + koff) * N + n0 + c];
  __syncthreads();
#pragma unroll
  for (int i = 0; i < 4; ++i)
    out[(size_t)(n0 + r + i * 8) * K + k0 + c] = f2bf(tile[c][r + i * 8] * scale);
}

// packed LSTM weight: out[(u*4+g)*K + k] = lstm_w[(k+koff)*4096 + g*1024 + u]
// grid (32, K/32, 4)
__global__ __launch_bounds__(256) void convt_perm_kernel(u16* __restrict__ out,
                                                         const float* __restrict__ in,
                                                         int K, int koff) {
  __shared__ float tile[32][33];
  const int tid = threadIdx.x;
  const int u0 = blockIdx.x * 32, k0 = blockIdx.y * 32, g = blockIdx.z;
  const int c = tid & 31, r = tid >> 5;
#pragma unroll
  for (int i = 0; i < 4; ++i)
    tile[r + i * 8][c] = in[(size_t)(k0 + r + i * 8 + koff) * 4096 + g * 1024 + u0 + c];
  __syncthreads();
#pragma unroll
  for (int i = 0; i < 4; ++i)
    out[(size_t)((u0 + r + i * 8) * 4 + g) * K + k0 + c] = f2bf(tile[c][r + i * 8]);
}

__global__ __launch_bounds__(256) void pack_bias_kernel(float* __restrict__ out,
                                                        const float* __restrict__ in) {
  int p = blockIdx.x * 256 + threadIdx.x;  // 4096
  out[p] = in[(p & 3) * 1024 + (p >> 2)];
}

// ---------------- GEMM: C[M,N] = A[M,K] @ Bt[N,K]^T (+bias, +cacc, relu, perm)
// 128x128 tile, BK=32, global_load_lds staging. grid (N/128, M/128), 256 thr.
// PERM==2: out row r -> (r&15)*512 + (r>>4)   (t*16+b -> b*512+t)
template <int OUTBF, int ACCUM, int RELU, int PERM>
__global__ __launch_bounds__(256) void gemm_bt_kernel(
    const u16* __restrict__ A, int lda, const u16* __restrict__ Bt,
    const float* __restrict__ bias, float bscale,
    void* __restrict__ outp, int ostride,
    const float* __restrict__ cacc, int cstride, int K) {
  __shared__ u16 As[128 * 32];
  __shared__ u16 Bs[128 * 32];
  const int tid = threadIdx.x;
  const int wave = tid >> 6, lane = tid & 63;
  const int lr = lane & 15, lg = lane >> 4;
  const int m0 = blockIdx.y * 128, n0 = blockIdx.x * 128;
  const int wr = (wave >> 1) * 64, wc = (wave & 1) * 64;

  f32x4 acc[4][4] = {};

  const int sr = lane >> 2, sce = (lane & 3) * 8;
  const u16* gA = A + (size_t)(m0 + wave * 16 + sr) * lda + sce;
  const u16* gB = Bt + (size_t)(n0 + wave * 16 + sr) * K + sce;
  u16* lA = As + wave * 16 * 32;
  u16* lB = Bs + wave * 16 * 32;

  for (int k0 = 0; k0 < K; k0 += 32) {
    __syncthreads();  // previous tile's compute done
    load_lds16(gA + k0, lA);
    load_lds16(gA + k0 + (size_t)64 * lda, lA + 64 * 32);
    load_lds16(gB + k0, lB);
    load_lds16(gB + k0 + (size_t)64 * K, lB + 64 * 32);
    __syncthreads();  // compiler drains vmcnt before barrier
    bf16x8 af[4], bfr[4];
    const u16* pa = As + (wr + lr) * 32 + lg * 8;
    const u16* pb = Bs + (wc + lr) * 32 + lg * 8;
#pragma unroll
    for (int i = 0; i < 4; ++i) af[i] = ldfrag(pa + i * 16 * 32);
#pragma unroll
    for (int j = 0; j < 4; ++j) bfr[j] = ldfrag(pb + j * 16 * 32);
#pragma unroll
    for (int i = 0; i < 4; ++i)
#pragma unroll
      for (int j = 0; j < 4; ++j)
        acc[i][j] = mfma_bf16(af[i], bfr[j], acc[i][j]);
  }

  const int col0 = n0 + wc + lr;
  const int row0 = m0 + wr + lg * 4;
#pragma unroll
  for (int i = 0; i < 4; ++i) {
#pragma unroll
    for (int j = 0; j < 4; ++j) {
      const int c = col0 + j * 16;
      const float bv = bias ? bias[c] * bscale : 0.f;
#pragma unroll
      for (int ii = 0; ii < 4; ++ii) {
        const int r = row0 + i * 16 + ii;
        float v = acc[i][j][ii] + bv;
        if (ACCUM) v += cacc[(size_t)r * cstride + c];
        if (RELU) v = fmaxf(v, 0.f);
        const int rp = (PERM == 2) ? ((r & 15) * 512 + (r >> 4)) : r;
        if (OUTBF) ((u16*)outp)[(size_t)rp * ostride + c] = f2bf(v);
        else       ((float*)outp)[(size_t)rp * ostride + c] = v;
      }
    }
  }
}

// ---------------- flash attention (validated R1/R2) ----------------
template <int CAUSAL>
__global__ __launch_bounds__(256) void flash_kernel(
    const u16* __restrict__ Q, const u16* __restrict__ Kb, const u16* __restrict__ Vb,
    const float* __restrict__ sbias, u16* __restrict__ O) {
  __shared__ u16 Kl[64 * 72];
  __shared__ u16 Vt[64 * 72];
  __shared__ u16 Pl[64 * 72];
  const int tid = threadIdx.x, wave = tid >> 6, lane = tid & 63;
  const int lr = lane & 15, lg = lane >> 4;
  const int q0 = blockIdx.x * 64, hh = blockIdx.y, b = blockIdx.z;

  bf16x8 qf[2];
  {
    const u16* qp = Q + (size_t)(b * 512 + q0 + wave * 16 + lr) * 1024 + hh * 64 + lg * 8;
    qf[0] = ldfrag(qp);
    qf[1] = ldfrag(qp + 32);
  }
  f32x4 oacc[4] = {};
  float mrun[4], lsum[4];
#pragma unroll
  for (int ii = 0; ii < 4; ++ii) { mrun[ii] = -3e38f; lsum[ii] = 0.f; }

  const int ntiles = CAUSAL ? (q0 / 64 + 1) : 8;
  for (int ti = 0; ti < ntiles; ++ti) {
    const int s0 = ti * 64;
    {
      const int r = tid >> 2, ch = (tid & 3) * 16;
      const u16* kp = Kb + (size_t)(b * 512 + s0 + r) * 1024 + hh * 64 + ch;
      const u16* vp = Vb + (size_t)(b * 512 + s0 + r) * 1024 + hh * 64 + ch;
      int32x4 k0v = *(const int32x4*)kp;
      int32x4 k1v = *(const int32x4*)(kp + 8);
      int32x4 v0v = *(const int32x4*)vp;
      int32x4 v1v = *(const int32x4*)(vp + 8);
      *(int32x4*)&Kl[r * 72 + ch] = k0v;
      *(int32x4*)&Kl[r * 72 + ch + 8] = k1v;
      const u16* v0p = (const u16*)&v0v;
      const u16* v1p = (const u16*)&v1v;
#pragma unroll
      for (int j = 0; j < 8; ++j) {
        Vt[(ch + j) * 72 + r] = v0p[j];
        Vt[(ch + 8 + j) * 72 + r] = v1p[j];
      }
    }
    __syncthreads();
    f32x4 sf[4] = {};
#pragma unroll
    for (int j = 0; j < 4; ++j)
#pragma unroll
      for (int ks = 0; ks < 2; ++ks) {
        bf16x8 kf = ldfrag(&Kl[(j * 16 + lr) * 72 + ks * 32 + lg * 8]);
        sf[j] = mfma_bf16(qf[ks], kf, sf[j]);
      }
    if (!CAUSAL) {
#pragma unroll
      for (int j = 0; j < 4; ++j) {
        const float bv = sbias[b * 512 + s0 + j * 16 + lr];
#pragma unroll
        for (int ii = 0; ii < 4; ++ii) sf[j][ii] += bv;
      }
    } else {
#pragma unroll
      for (int j = 0; j < 4; ++j) {
        const int s = s0 + j * 16 + lr;
#pragma unroll
        for (int ii = 0; ii < 4; ++ii) {
          const int q = q0 + wave * 16 + lg * 4 + ii;
          if (s > q) sf[j][ii] -= 1e9f;
        }
      }
    }
    float sc[4], rs[4];
#pragma unroll
    for (int ii = 0; ii < 4; ++ii) {
      float m = fmaxf(fmaxf(sf[0][ii], sf[1][ii]), fmaxf(sf[2][ii], sf[3][ii]));
#pragma unroll
      for (int off = 1; off < 16; off <<= 1) m = fmaxf(m, __shfl_xor(m, off));
      const float mn = fmaxf(mrun[ii], m);
      sc[ii] = __expf(mrun[ii] - mn);
      mrun[ii] = mn;
      rs[ii] = 0.f;
    }
#pragma unroll
    for (int j = 0; j < 4; ++j)
#pragma unroll
      for (int ii = 0; ii < 4; ++ii) {
        const float p = __expf(sf[j][ii] - mrun[ii]);
        rs[ii] += p;
        Pl[(wave * 16 + lg * 4 + ii) * 72 + j * 16 + lr] = f2bf(p);
      }
#pragma unroll
    for (int ii = 0; ii < 4; ++ii) {
      float r = rs[ii];
#pragma unroll
      for (int off = 1; off < 16; off <<= 1) r += __shfl_xor(r, off);
      lsum[ii] = lsum[ii] * sc[ii] + r;
    }
#pragma unroll
    for (int df = 0; df < 4; ++df)
#pragma unroll
      for (int ii = 0; ii < 4; ++ii) oacc[df][ii] *= sc[ii];
    __syncthreads();
    bf16x8 pf[2];
    pf[0] = ldfrag(&Pl[(wave * 16 + lr) * 72 + lg * 8]);
    pf[1] = ldfrag(&Pl[(wave * 16 + lr) * 72 + 32 + lg * 8]);
#pragma unroll
    for (int df = 0; df < 4; ++df)
#pragma unroll
      for (int ks = 0; ks < 2; ++ks) {
        bf16x8 vf = ldfrag(&Vt[(df * 16 + lr) * 72 + ks * 32 + lg * 8]);
        oacc[df] = mfma_bf16(pf[ks], vf, oacc[df]);
      }
    __syncthreads();
  }
#pragma unroll
  for (int df = 0; df < 4; ++df)
#pragma unroll
    for (int ii = 0; ii < 4; ++ii) {
      const float v = oacc[df][ii] / lsum[ii];
      O[(size_t)(b * 512 + q0 + wave * 16 + lg * 4 + ii) * 1024 + hh * 64 + df * 16 + lr] =
          f2bf(v);
    }
}

// ---------------- persistent LSTM scan R8: anti-phase batch groups ----------------
// 32 WGs x 256 thr. WG g owns units [g*32,+32). Two independent batch groups
// (A: 0-7, B: 8-15) alternate half-slots; each group's publish->L3->detect
// latency hides under the other group's compute. Split-K per wave (K-quarter),
// sentinel data-poll (R7). MFMA A-rows 8-15 duplicate rows 0-7 (unused).
#define SCAN_NW 32
__global__ __launch_bounds__(256, 1) void lstm_scan_kernel(
    const u16* __restrict__ Whp, const float* __restrict__ gx,
    u16* __restrict__ hbuf) {
  const int tid = threadIdx.x, wave = tid >> 6, lane = tid & 63;
  const int lr = lane & 15, lg = lane >> 4;
  const int g = blockIdx.x;
  __shared__ float part[2][4][8][132];   // [group][wave][batch][pcol pad] 33.8KB
  const int gb = tid >> 5;               // gate-phase batch row 0..7 (in-group)
  const int uu = tid & 31;               // gate-phase unit 0..31
  float csA = 0.f, csB = 0.f;
  const u64 SENT = 0xFFFFFFFFFFFFFFFFull;

  // B-operand base: col-tile j (16 pcols), chunk kc -> wbase + j*16*1024 + kc*32
  const u16* wbase = Whp + (size_t)(g * 128 + lr) * 1024 + wave * 256 + lg * 8;
  const float* gxpA = gx + (size_t)gb * 512 * 4096 + g * 128 + uu * 4;
  const float* gxpB = gxpA + (size_t)8 * 512 * 4096;
  // gather bases (row = batch within group, duplicated across lr>=8)
  const size_t goffA = (size_t)(lr & 7) * 1024 + wave * 256 + lg * 8;
  const size_t goffB = goffA + 8 * 1024;

  u64 hwA[16], hwB[16];
#define ISSUE(hw, base, t)                                                        \
  {                                                                               \
    const u16* hp_ = hbuf + (size_t)(t) * 16384 + (base);                         \
    _Pragma("unroll") for (int kc = 0; kc < 8; ++kc) {                            \
      hw[kc * 2] = __hip_atomic_load((const u64*)(hp_ + kc * 32),                 \
                                     __ATOMIC_RELAXED, __HIP_MEMORY_SCOPE_AGENT); \
      hw[kc * 2 + 1] = __hip_atomic_load((const u64*)(hp_ + kc * 32 + 4),         \
                                         __ATOMIC_RELAXED,                       \
                                         __HIP_MEMORY_SCOPE_AGENT);              \
    }                                                                             \
  }
#define SPINFIX(hw, base, t)                                                      \
  {                                                                               \
    const u16* hp_ = hbuf + (size_t)(t) * 16384 + (base);                         \
    int guard_ = 0;                                                               \
    for (;;) {                                                                    \
      bool ok_ = true;                                                            \
      _Pragma("unroll") for (int i = 0; i < 16; ++i) ok_ &= (hw[i] != SENT);      \
      if (__all((int)ok_)) break;                                                 \
      __builtin_amdgcn_s_sleep(2);                                                \
      if (++guard_ > (1 << 20)) break;                                            \
      _Pragma("unroll") for (int kc = 0; kc < 8; ++kc) {                          \
        if (hw[kc * 2] == SENT)                                                   \
          hw[kc * 2] = __hip_atomic_load((const u64*)(hp_ + kc * 32),             \
                                         __ATOMIC_RELAXED,                       \
                                         __HIP_MEMORY_SCOPE_AGENT);              \
        if (hw[kc * 2 + 1] == SENT)                                               \
          hw[kc * 2 + 1] = __hip_atomic_load((const u64*)(hp_ + kc * 32 + 4),     \
                                             __ATOMIC_RELAXED,                   \
                                             __HIP_MEMORY_SCOPE_AGENT);          \
      }                                                                           \
    }                                                                             \
  }
#define MFMA_PART(grp, hw)                                                        \
  {                                                                               \
    f32x4 acc_[8] = {};                                                           \
    _Pragma("unroll") for (int kc = 0; kc < 8; ++kc) {                            \
      const bf16x8 hf_ = mkfrag(hw[kc * 2], hw[kc * 2 + 1]);                      \
      _Pragma("unroll") for (int j = 0; j < 8; ++j)                               \
          acc_[j] = mfma_bf16(hf_, ldfrag(wbase + j * 16 * 1024 + kc * 32),       \
                              acc_[j]);                                           \
    }                                                                             \
    if (lg < 2) {                                                                 \
      _Pragma("unroll") for (int j = 0; j < 8; ++j)                               \
          _Pragma("unroll") for (int ii = 0; ii < 4; ++ii)                        \
          part[grp][wave][lg * 4 + ii][j * 16 + lr] = acc_[j][ii];                \
    }                                                                             \
  }
#define GATES_PUB(grp, cs, gxv, bglob, t)                                         \
  {                                                                               \
    float4 s_ = *(const float4*)&part[grp][0][gb][uu * 4];                        \
    _Pragma("unroll") for (int w_ = 1; w_ < 4; ++w_) {                            \
      const float4 v_ = *(const float4*)&part[grp][w_][gb][uu * 4];               \
      s_.x += v_.x; s_.y += v_.y; s_.z += v_.z; s_.w += v_.w;                     \
    }                                                                             \
    const float si_ = s_.x + gxv.x, sj_ = s_.y + gxv.y;                           \
    const float sf_ = s_.z + gxv.z, so_ = s_.w + gxv.w;                           \
    const float ig_ = 1.f / (1.f + __expf(-si_));                                 \
    const float jg_ = 1.f - 2.f / (__expf(2.f * sj_) + 1.f);                      \
    const float fg_ = 1.f / (1.f + __expf(-sf_));                                 \
    const float og_ = 1.f / (1.f + __expf(-so_));                                 \
    cs = fg_ * cs + ig_ * jg_;                                                    \
    const float hn_ = og_ * (1.f - 2.f / (__expf(2.f * cs) + 1.f));               \
    const u32 w16_ = (u32)f2bf(hn_);                                              \
    const u32 p2_ = w16_ | ((u32)__shfl_down((int)w16_, 1) << 16);                \
    const u64 p4_ = (u64)p2_ | ((u64)(u32)__shfl_down((int)p2_, 2) << 32);        \
    if ((uu & 3) == 0) {                                                          \
      u64* dst_ = (u64*)(hbuf + (size_t)((t) + 1) * 16384 + (size_t)(bglob) * 1024 \
                         + g * 32 + uu);                                          \
      __hip_atomic_store(dst_, p4_, __ATOMIC_RELAXED, __HIP_MEMORY_SCOPE_AGENT);  \
    }                                                                             \
  }

  ISSUE(hwA, goffA, 0);  // prologue: h_0 (zeros, ready)
  for (int t = 0; t < 512; ++t) {
    // gx for both groups, issued early (HBM latency hides under spin/compute)
    const float4 gxvA = *(const float4*)(gxpA + (size_t)t * 4096);
    const float4 gxvB = *(const float4*)(gxpB + (size_t)t * 4096);
    // ---- phase A ----
    SPINFIX(hwA, goffA, t);
    ISSUE(hwB, goffB, t);                 // prefetch B (published one half-slot ago)
    __builtin_amdgcn_sched_barrier(0);    // keep B-issue ahead of MFMA cluster
    MFMA_PART(0, hwA);
    __syncthreads();
    GATES_PUB(0, csA, gxvA, gb, t);
    // ---- phase B ----
    SPINFIX(hwB, goffB, t);
    if (t + 1 < 512) ISSUE(hwA, goffA, t + 1);  // prefetch next A (just published)
    __builtin_amdgcn_sched_barrier(0);
    MFMA_PART(1, hwB);
    __syncthreads();
    GATES_PUB(1, csB, gxvB, gb + 8, t);
  }
#undef ISSUE
#undef SPINFIX
#undef MFMA_PART
#undef GATES_PUB
}

// ---------------- host ----------------

extern "C" void kernel_launch(void* const* d_in, const int* in_sizes, int n_in,
                              void* d_out, int out_size, void* d_ws, size_t ws_size,
                              hipStream_t stream) {
  const float* x        = (const float*)d_in[0];
  const float* mem      = (const float*)d_in[1];
  const float* src_bias = (const float*)d_in[2];
  const float* w_src_q = (const float*)d_in[4];  const float* b_src_q = (const float*)d_in[5];
  const float* w_src_k = (const float*)d_in[6];  const float* b_src_k = (const float*)d_in[7];
  const float* w_src_v = (const float*)d_in[8];  const float* b_src_v = (const float*)d_in[9];
  const float* w_src_o = (const float*)d_in[10]; const float* b_src_o = (const float*)d_in[11];
  const float* w_tgt_q = (const float*)d_in[12]; const float* b_tgt_q = (const float*)d_in[13];
  const float* w_tgt_k = (const float*)d_in[14]; const float* b_tgt_k = (const float*)d_in[15];
  const float* w_tgt_v = (const float*)d_in[16]; const float* b_tgt_v = (const float*)d_in[17];
  const float* w_tgt_o = (const float*)d_in[18]; const float* b_tgt_o = (const float*)d_in[19];
  const float* lstm_w  = (const float*)d_in[20]; const float* lstm_b  = (const float*)d_in[21];
  const float* w1 = (const float*)d_in[22]; const float* b1f = (const float*)d_in[23];
  const float* w2 = (const float*)d_in[24]; const float* b2f = (const float*)d_in[25];

  char* ws = (char*)d_ws;
  const size_t MiB = 1024ull * 1024ull;
  u16*   xcb  = (u16*)(ws + 0);             // [8192][2048]: cols 0-1023 x, 1024+ c
  u16*   wlp  = (u16*)(ws + 32 * MiB);      // [4096 packed][2048]
  u16*   whp  = (u16*)(ws + 48 * MiB);      // [4096 packed][1024]
  u16*   w1t  = (u16*)(ws + 56 * MiB);
  u16*   w2t  = (u16*)(ws + 64 * MiB);
  float* pb   = (float*)(ws + 72 * MiB);    // packed lstm bias [4096]
  u16*   hbuf = (u16*)(ws + 73 * MiB);      // [513][16][1024]
  u16*   memb = (u16*)(ws + 90 * MiB);
  u16*   wt[8];
  for (int i = 0; i < 8; ++i) wt[i] = (u16*)(ws + 106 * MiB + (size_t)i * 2 * MiB);
  u16*   bq   = (u16*)(ws + 122 * MiB);
  u16*   bk   = (u16*)(ws + 138 * MiB);
  u16*   bv   = (u16*)(ws + 154 * MiB);
  u16*   ao_s = (u16*)(ws + 170 * MiB);
  u16*   ao_t = (u16*)(ws + 186 * MiB);
  float* c32  = (float*)(ws + 202 * MiB);   // ..234
  float* gx   = (float*)(ws + 90 * MiB);    // overlay 90..218 (after attention)
  u16*   ffn1 = (u16*)(ws + 90 * MiB);      // overlay 90..154 (after scan)

  // sentinel-fill h rows 1..512 FIRST (L2 copies evicted by ~1ms of GEMM
  // traffic before FFN's cached reads; scan polls via L2-bypass regardless)
  hipMemsetAsync(hbuf + 16384, 0xFF, (size_t)512 * 16384 * 2, stream);
  hipMemsetAsync(hbuf, 0, 32768, stream);   // h_0 = 0

  // --- conversions ---
  cvt_x_kernel<<<8192, 256, 0, stream>>>(xcb, x);
  cvt_bf16_kernel<<<8192, 256, 0, stream>>>(memb, mem, 2097152);
  const dim3 g1k(32, 32);
  convt_kernel<<<g1k, 256, 0, stream>>>(wt[0], w_src_q, 1024, 1024, 0, 0.125f);
  convt_kernel<<<g1k, 256, 0, stream>>>(wt[1], w_src_k, 1024, 1024, 0, 1.f);
  convt_kernel<<<g1k, 256, 0, stream>>>(wt[2], w_src_v, 1024, 1024, 0, 1.f);
  convt_kernel<<<g1k, 256, 0, stream>>>(wt[3], w_src_o, 1024, 1024, 0, 1.f);
  convt_kernel<<<g1k, 256, 0, stream>>>(wt[4], w_tgt_q, 1024, 1024, 0, 0.125f);
  convt_kernel<<<g1k, 256, 0, stream>>>(wt[5], w_tgt_k, 1024, 1024, 0, 1.f);
  convt_kernel<<<g1k, 256, 0, stream>>>(wt[6], w_tgt_v, 1024, 1024, 0, 1.f);
  convt_kernel<<<g1k, 256, 0, stream>>>(wt[7], w_tgt_o, 1024, 1024, 0, 1.f);
  convt_perm_kernel<<<dim3(32, 64, 4), 256, 0, stream>>>(wlp, lstm_w, 2048, 0);
  convt_perm_kernel<<<dim3(32, 32, 4), 256, 0, stream>>>(whp, lstm_w, 1024, 2048);
  convt_kernel<<<dim3(128, 32), 256, 0, stream>>>(w1t, w1, 1024, 4096, 0, 1.f);
  convt_kernel<<<dim3(32, 128), 256, 0, stream>>>(w2t, w2, 4096, 1024, 0, 1.f);
  pack_bias_kernel<<<16, 256, 0, stream>>>(pb, lstm_b);

  const dim3 gN1(8, 64);   // N=1024
  const dim3 gN4(32, 64);  // N=4096

  // --- src attention ---
  gemm_bt_kernel<1, 0, 0, 0><<<gN1, 256, 0, stream>>>(xcb, 2048, wt[0], b_src_q, 0.125f, bq, 1024, nullptr, 0, 1024);
  gemm_bt_kernel<1, 0, 0, 0><<<gN1, 256, 0, stream>>>(memb, 1024, wt[1], b_src_k, 1.f, bk, 1024, nullptr, 0, 1024);
  gemm_bt_kernel<1, 0, 0, 0><<<gN1, 256, 0, stream>>>(memb, 1024, wt[2], b_src_v, 1.f, bv, 1024, nullptr, 0, 1024);
  flash_kernel<0><<<dim3(8, 16, 16), 256, 0, stream>>>(bq, bk, bv, src_bias, ao_s);
  // --- tgt (causal self) attention ---
  gemm_bt_kernel<1, 0, 0, 0><<<gN1, 256, 0, stream>>>(xcb, 2048, wt[4], b_tgt_q, 0.125f, bq, 1024, nullptr, 0, 1024);
  gemm_bt_kernel<1, 0, 0, 0><<<gN1, 256, 0, stream>>>(xcb, 2048, wt[5], b_tgt_k, 1.f, bk, 1024, nullptr, 0, 1024);
  gemm_bt_kernel<1, 0, 0, 0><<<gN1, 256, 0, stream>>>(xcb, 2048, wt[6], b_tgt_v, 1.f, bv, 1024, nullptr, 0, 1024);
  flash_kernel<1><<<dim3(8, 16, 16), 256, 0, stream>>>(bq, bk, bv, nullptr, ao_t);
  // --- c = ao_s@Wo_s + bo_s + ao_t@Wo_t + bo_t -> xcb cols 1024+ (bf16) ---
  gemm_bt_kernel<0, 0, 0, 0><<<gN1, 256, 0, stream>>>(ao_s, 1024, wt[3], b_src_o, 1.f, c32, 1024, nullptr, 0, 1024);
  gemm_bt_kernel<1, 1, 0, 0><<<gN1, 256, 0, stream>>>(ao_t, 1024, wt[7], b_tgt_o, 1.f, xcb + 1024, 2048, c32, 1024, 1024);
  // --- gx = [x|c] @ wlp^T + pb  (K=2048, packed cols) ---
  gemm_bt_kernel<0, 0, 0, 0><<<gN4, 256, 0, stream>>>(xcb, 2048, wlp, pb, 1.f, gx, 4096, nullptr, 0, 2048);
  // --- LSTM scan: single persistent kernel, 32 WGs (all co-resident) ---
  lstm_scan_kernel<<<dim3(SCAN_NW), 256, 0, stream>>>(whp, gx, hbuf);
  // --- FFN ---
  gemm_bt_kernel<1, 0, 1, 0><<<gN4, 256, 0, stream>>>(hbuf + 16384, 1024, w1t, b1f, 1.f, ffn1, 4096, nullptr, 0, 1024);
  gemm_bt_kernel<0, 0, 0, 2><<<gN1, 256, 0, stream>>>(ffn1, 4096, w2t, b2f, 1.f, (float*)d_out, 1024, nullptr, 0, 4096);
}

// Round 9
// 3250.999 us; speedup vs baseline: 1.3959x; 1.3959x over previous
//
#include <hip/hip_runtime.h>
#include <hip/hip_bf16.h>
#include <stdint.h>

// ---------------------------------------------------------------------------
// DeepLSTMDecoderLayer R9:
//  - GEMMs: 128x128 tile, BK=32, global_load_lds width-16 staging (m97-style)
//  - flash attention 64x64 (validated R1/R2)
//  - LSTM scan: R7 structure (sentinel data-poll, split-K, 1 barrier/step) +
//    polish: gx prefetched one step ahead (off the spin vmcnt path), gather
//    re-issued at loop tail right after publish, padded part[...][132].
//  - FFN1 FUSED: grid 224 = 32 scan WGs + 192 worker WGs (80KB LDS -> 1
//    WG/CU, disjoint CUs). Workers sentinel-poll a tile's LAST timestep rows
//    (monotone publication), then run a normal cacheable gemm tile of
//    relu(h@W1+b1). ffn1 lives in dead ws regions (0..48MiB + 218..234MiB,
//    split at row 6144); FFN2 = two launches with row offset.
// ws at scan time: 0..48 ffn1_r0 (over dead xcb+wlp) | 48 whp | 56 w1t |
//   64 w2t | 72 pb | 73 hbuf | 90..218 gx | 218..234 ffn1_r1 (dead c32 tail)
// ---------------------------------------------------------------------------

typedef unsigned short u16;
typedef unsigned int u32;
typedef unsigned long long u64;
typedef __bf16 bf16x8 __attribute__((ext_vector_type(8)));
typedef float f32x4 __attribute__((ext_vector_type(4)));
typedef int int32x4 __attribute__((ext_vector_type(4)));
typedef unsigned long long u64x2 __attribute__((ext_vector_type(2)));

#define DEV static __device__ __forceinline__

DEV u16 f2bf(float x) {
  u32 u = __builtin_bit_cast(u32, x);
  u += 0x7FFF + ((u >> 16) & 1);  // round-to-nearest-even
  return (u16)(u >> 16);
}

DEV bf16x8 ldfrag(const void* p) {
  int32x4 v = *(const int32x4*)p;
  return __builtin_bit_cast(bf16x8, v);
}

DEV bf16x8 mkfrag(u64 lo, u64 hi) {
  u64x2 v;
  v.x = lo;
  v.y = hi;
  return __builtin_bit_cast(bf16x8, v);
}

DEV f32x4 mfma_bf16(bf16x8 a, bf16x8 b, f32x4 c) {
  return __builtin_amdgcn_mfma_f32_16x16x32_bf16(a, b, c, 0, 0, 0);
}

DEV u64 aload(const u64* p) {
  return __hip_atomic_load(p, __ATOMIC_RELAXED, __HIP_MEMORY_SCOPE_AGENT);
}

// async global->LDS, 16B per lane; LDS dest is wave-uniform base (+lane*16 HW)
DEV void load_lds16(const u16* g, u16* l) {
  __builtin_amdgcn_global_load_lds(
      (__attribute__((address_space(1))) void*)(uintptr_t)g,
      (__attribute__((address_space(3))) void*)(uintptr_t)l, 16, 0, 0);
}

// ---------------- conversion kernels ----------------

__global__ __launch_bounds__(256) void cvt_bf16_kernel(u16* __restrict__ out,
                                                       const float* __restrict__ in,
                                                       int n4) {
  int i = blockIdx.x * 256 + threadIdx.x;
  if (i >= n4) return;
  float4 v = ((const float4*)in)[i];
  ushort4 s;
  s.x = f2bf(v.x); s.y = f2bf(v.y); s.z = f2bf(v.z); s.w = f2bf(v.w);
  ((ushort4*)out)[i] = s;
}

// x[8192][1024] f32 -> xcb[r][0..1023] with row stride 2048
__global__ __launch_bounds__(256) void cvt_x_kernel(u16* __restrict__ out,
                                                    const float* __restrict__ in) {
  int i = blockIdx.x * 256 + threadIdx.x;
  int r = i >> 8, cg4 = i & 255;
  float4 v = ((const float4*)in)[i];
  ushort4 s;
  s.x = f2bf(v.x); s.y = f2bf(v.y); s.z = f2bf(v.z); s.w = f2bf(v.w);
  *(ushort4*)(out + (size_t)r * 2048 + cg4 * 4) = s;
}

// out[n*K + k] = in[(k+koff)*N + n] * scale
__global__ __launch_bounds__(256) void convt_kernel(u16* __restrict__ out,
                                                    const float* __restrict__ in,
                                                    int K, int N, int koff, float scale) {
  __shared__ float tile[32][33];
  const int tid = threadIdx.x;
  const int n0 = blockIdx.x * 32, k0 = blockIdx.y * 32;
  const int c = tid & 31, r = tid >> 5;
#pragma unroll
  for (int i = 0; i < 4; ++i)
    tile[r + i * 8][c] = in[(size_t)(k0 + r + i * 8 + koff) * N + n0 + c];
  __syncthreads();
#pragma unroll
  for (int i = 0; i < 4; ++i)
    out[(size_t)(n0 + r + i * 8) * K + k0 + c] = f2bf(tile[c][r + i * 8] * scale);
}

// packed LSTM weight: out[(u*4+g)*K + k] = lstm_w[(k+koff)*4096 + g*1024 + u]
__global__ __launch_bounds__(256) void convt_perm_kernel(u16* __restrict__ out,
                                                         const float* __restrict__ in,
                                                         int K, int koff) {
  __shared__ float tile[32][33];
  const int tid = threadIdx.x;
  const int u0 = blockIdx.x * 32, k0 = blockIdx.y * 32, g = blockIdx.z;
  const int c = tid & 31, r = tid >> 5;
#pragma unroll
  for (int i = 0; i < 4; ++i)
    tile[r + i * 8][c] = in[(size_t)(k0 + r + i * 8 + koff) * 4096 + g * 1024 + u0 + c];
  __syncthreads();
#pragma unroll
  for (int i = 0; i < 4; ++i)
    out[(size_t)((u0 + r + i * 8) * 4 + g) * K + k0 + c] = f2bf(tile[c][r + i * 8]);
}

__global__ __launch_bounds__(256) void pack_bias_kernel(float* __restrict__ out,
                                                        const float* __restrict__ in) {
  int p = blockIdx.x * 256 + threadIdx.x;  // 4096
  out[p] = in[(p & 3) * 1024 + (p >> 2)];
}

// ---------------- GEMM: C[M,N] = A[M,K] @ Bt[N,K]^T (+bias, +cacc, relu, perm)
// PERM==2: out row (moff+r) -> ((moff+r)&15)*512 + ((moff+r)>>4)
template <int OUTBF, int ACCUM, int RELU, int PERM>
__global__ __launch_bounds__(256) void gemm_bt_kernel(
    const u16* __restrict__ A, int lda, const u16* __restrict__ Bt,
    const float* __restrict__ bias, float bscale,
    void* __restrict__ outp, int ostride,
    const float* __restrict__ cacc, int cstride, int K, int moff) {
  __shared__ u16 As[128 * 32];
  __shared__ u16 Bs[128 * 32];
  const int tid = threadIdx.x;
  const int wave = tid >> 6, lane = tid & 63;
  const int lr = lane & 15, lg = lane >> 4;
  const int m0 = blockIdx.y * 128, n0 = blockIdx.x * 128;
  const int wr = (wave >> 1) * 64, wc = (wave & 1) * 64;

  f32x4 acc[4][4] = {};

  const int sr = lane >> 2, sce = (lane & 3) * 8;
  const u16* gA = A + (size_t)(m0 + wave * 16 + sr) * lda + sce;
  const u16* gB = Bt + (size_t)(n0 + wave * 16 + sr) * K + sce;
  u16* lA = As + wave * 16 * 32;
  u16* lB = Bs + wave * 16 * 32;

  for (int k0 = 0; k0 < K; k0 += 32) {
    __syncthreads();
    load_lds16(gA + k0, lA);
    load_lds16(gA + k0 + (size_t)64 * lda, lA + 64 * 32);
    load_lds16(gB + k0, lB);
    load_lds16(gB + k0 + (size_t)64 * K, lB + 64 * 32);
    __syncthreads();
    bf16x8 af[4], bfr[4];
    const u16* pa = As + (wr + lr) * 32 + lg * 8;
    const u16* pb = Bs + (wc + lr) * 32 + lg * 8;
#pragma unroll
    for (int i = 0; i < 4; ++i) af[i] = ldfrag(pa + i * 16 * 32);
#pragma unroll
    for (int j = 0; j < 4; ++j) bfr[j] = ldfrag(pb + j * 16 * 32);
#pragma unroll
    for (int i = 0; i < 4; ++i)
#pragma unroll
      for (int j = 0; j < 4; ++j)
        acc[i][j] = mfma_bf16(af[i], bfr[j], acc[i][j]);
  }

  const int col0 = n0 + wc + lr;
  const int row0 = m0 + wr + lg * 4;
#pragma unroll
  for (int i = 0; i < 4; ++i) {
#pragma unroll
    for (int j = 0; j < 4; ++j) {
      const int c = col0 + j * 16;
      const float bv = bias ? bias[c] * bscale : 0.f;
#pragma unroll
      for (int ii = 0; ii < 4; ++ii) {
        const int r = row0 + i * 16 + ii;
        float v = acc[i][j][ii] + bv;
        if (ACCUM) v += cacc[(size_t)r * cstride + c];
        if (RELU) v = fmaxf(v, 0.f);
        const int gr = moff + r;
        const int rp = (PERM == 2) ? ((gr & 15) * 512 + (gr >> 4)) : r;
        if (OUTBF) ((u16*)outp)[(size_t)rp * ostride + c] = f2bf(v);
        else       ((float*)outp)[(size_t)rp * ostride + c] = v;
      }
    }
  }
}

// ---------------- flash attention (validated R1/R2) ----------------
template <int CAUSAL>
__global__ __launch_bounds__(256) void flash_kernel(
    const u16* __restrict__ Q, const u16* __restrict__ Kb, const u16* __restrict__ Vb,
    const float* __restrict__ sbias, u16* __restrict__ O) {
  __shared__ u16 Kl[64 * 72];
  __shared__ u16 Vt[64 * 72];
  __shared__ u16 Pl[64 * 72];
  const int tid = threadIdx.x, wave = tid >> 6, lane = tid & 63;
  const int lr = lane & 15, lg = lane >> 4;
  const int q0 = blockIdx.x * 64, hh = blockIdx.y, b = blockIdx.z;

  bf16x8 qf[2];
  {
    const u16* qp = Q + (size_t)(b * 512 + q0 + wave * 16 + lr) * 1024 + hh * 64 + lg * 8;
    qf[0] = ldfrag(qp);
    qf[1] = ldfrag(qp + 32);
  }
  f32x4 oacc[4] = {};
  float mrun[4], lsum[4];
#pragma unroll
  for (int ii = 0; ii < 4; ++ii) { mrun[ii] = -3e38f; lsum[ii] = 0.f; }

  const int ntiles = CAUSAL ? (q0 / 64 + 1) : 8;
  for (int ti = 0; ti < ntiles; ++ti) {
    const int s0 = ti * 64;
    {
      const int r = tid >> 2, ch = (tid & 3) * 16;
      const u16* kp = Kb + (size_t)(b * 512 + s0 + r) * 1024 + hh * 64 + ch;
      const u16* vp = Vb + (size_t)(b * 512 + s0 + r) * 1024 + hh * 64 + ch;
      int32x4 k0v = *(const int32x4*)kp;
      int32x4 k1v = *(const int32x4*)(kp + 8);
      int32x4 v0v = *(const int32x4*)vp;
      int32x4 v1v = *(const int32x4*)(vp + 8);
      *(int32x4*)&Kl[r * 72 + ch] = k0v;
      *(int32x4*)&Kl[r * 72 + ch + 8] = k1v;
      const u16* v0p = (const u16*)&v0v;
      const u16* v1p = (const u16*)&v1v;
#pragma unroll
      for (int j = 0; j < 8; ++j) {
        Vt[(ch + j) * 72 + r] = v0p[j];
        Vt[(ch + 8 + j) * 72 + r] = v1p[j];
      }
    }
    __syncthreads();
    f32x4 sf[4] = {};
#pragma unroll
    for (int j = 0; j < 4; ++j)
#pragma unroll
      for (int ks = 0; ks < 2; ++ks) {
        bf16x8 kf = ldfrag(&Kl[(j * 16 + lr) * 72 + ks * 32 + lg * 8]);
        sf[j] = mfma_bf16(qf[ks], kf, sf[j]);
      }
    if (!CAUSAL) {
#pragma unroll
      for (int j = 0; j < 4; ++j) {
        const float bv = sbias[b * 512 + s0 + j * 16 + lr];
#pragma unroll
        for (int ii = 0; ii < 4; ++ii) sf[j][ii] += bv;
      }
    } else {
#pragma unroll
      for (int j = 0; j < 4; ++j) {
        const int s = s0 + j * 16 + lr;
#pragma unroll
        for (int ii = 0; ii < 4; ++ii) {
          const int q = q0 + wave * 16 + lg * 4 + ii;
          if (s > q) sf[j][ii] -= 1e9f;
        }
      }
    }
    float sc[4], rs[4];
#pragma unroll
    for (int ii = 0; ii < 4; ++ii) {
      float m = fmaxf(fmaxf(sf[0][ii], sf[1][ii]), fmaxf(sf[2][ii], sf[3][ii]));
#pragma unroll
      for (int off = 1; off < 16; off <<= 1) m = fmaxf(m, __shfl_xor(m, off));
      const float mn = fmaxf(mrun[ii], m);
      sc[ii] = __expf(mrun[ii] - mn);
      mrun[ii] = mn;
      rs[ii] = 0.f;
    }
#pragma unroll
    for (int j = 0; j < 4; ++j)
#pragma unroll
      for (int ii = 0; ii < 4; ++ii) {
        const float p = __expf(sf[j][ii] - mrun[ii]);
        rs[ii] += p;
        Pl[(wave * 16 + lg * 4 + ii) * 72 + j * 16 + lr] = f2bf(p);
      }
#pragma unroll
    for (int ii = 0; ii < 4; ++ii) {
      float r = rs[ii];
#pragma unroll
      for (int off = 1; off < 16; off <<= 1) r += __shfl_xor(r, off);
      lsum[ii] = lsum[ii] * sc[ii] + r;
    }
#pragma unroll
    for (int df = 0; df < 4; ++df)
#pragma unroll
      for (int ii = 0; ii < 4; ++ii) oacc[df][ii] *= sc[ii];
    __syncthreads();
    bf16x8 pf[2];
    pf[0] = ldfrag(&Pl[(wave * 16 + lr) * 72 + lg * 8]);
    pf[1] = ldfrag(&Pl[(wave * 16 + lr) * 72 + 32 + lg * 8]);
#pragma unroll
    for (int df = 0; df < 4; ++df)
#pragma unroll
      for (int ks = 0; ks < 2; ++ks) {
        bf16x8 vf = ldfrag(&Vt[(df * 16 + lr) * 72 + ks * 32 + lg * 8]);
        oacc[df] = mfma_bf16(pf[ks], vf, oacc[df]);
      }
    __syncthreads();
  }
#pragma unroll
  for (int df = 0; df < 4; ++df)
#pragma unroll
    for (int ii = 0; ii < 4; ++ii) {
      const float v = oacc[df][ii] / lsum[ii];
      O[(size_t)(b * 512 + q0 + wave * 16 + lg * 4 + ii) * 1024 + hh * 64 + df * 16 + lr] =
          f2bf(v);
    }
}

// ---------------- fused scan + FFN1 workers ----------------
// grid 224: WGs 0..31 = LSTM scan (R7 + polish); WGs 32..223 = FFN1 workers.
// Dynamic smem pads LDS to 80KB -> 1 WG/CU -> scan and workers on disjoint CUs.
#define SCAN_NW 32
#define NWORK 192
__global__ __launch_bounds__(256, 1) void lstm_scan_kernel(
    const u16* __restrict__ Whp, const float* __restrict__ gx,
    u16* __restrict__ hbuf, const u16* __restrict__ w1t,
    const float* __restrict__ b1f, u16* __restrict__ f0, u16* __restrict__ f1) {
  const int tid = threadIdx.x, wave = tid >> 6, lane = tid & 63;
  const int lr = lane & 15, lg = lane >> 4;
  const int g = blockIdx.x;
  __shared__ float part[2][4][16][132];  // 67.6 KB; workers alias first 16 KB
  const u64 SENT = 0xFFFFFFFFFFFFFFFFull;

  if (g < SCAN_NW) {
    // ================= scan branch (R7 + polish) =================
    const int gb = tid >> 4;  // gate-phase batch row 0..15
    const int up = tid & 15;  // gate-phase unit pair: 2up, 2up+1
    float cs0 = 0.f, cs1 = 0.f;
    const u16* wbase = Whp + (size_t)(g * 128 + lr) * 1024 + wave * 256 + lg * 8;
    const float* gxp = gx + (size_t)gb * 512 * 4096 + g * 128 + up * 8;
    const size_t goff = (size_t)lr * 1024 + wave * 256 + lg * 8;

    u64 hw[16];
#define ISSUE(t)                                                               \
  {                                                                            \
    const u16* hp_ = hbuf + (size_t)(t) * 16384 + goff;                        \
    _Pragma("unroll") for (int kc = 0; kc < 8; ++kc) {                         \
      hw[kc * 2] = aload((const u64*)(hp_ + kc * 32));                         \
      hw[kc * 2 + 1] = aload((const u64*)(hp_ + kc * 32 + 4));                 \
    }                                                                          \
  }
#define SPINFIX(t)                                                             \
  {                                                                            \
    const u16* hp_ = hbuf + (size_t)(t) * 16384 + goff;                        \
    int guard_ = 0;                                                            \
    for (;;) {                                                                 \
      bool ok_ = true;                                                         \
      _Pragma("unroll") for (int i = 0; i < 16; ++i) ok_ &= (hw[i] != SENT);   \
      if (__all((int)ok_)) break;                                              \
      __builtin_amdgcn_s_sleep(2);                                             \
      if (++guard_ > (1 << 20)) break;                                         \
      _Pragma("unroll") for (int kc = 0; kc < 8; ++kc) {                       \
        if (hw[kc * 2] == SENT)                                                \
          hw[kc * 2] = aload((const u64*)(hp_ + kc * 32));                     \
        if (hw[kc * 2 + 1] == SENT)                                            \
          hw[kc * 2 + 1] = aload((const u64*)(hp_ + kc * 32 + 4));             \
      }                                                                        \
    }                                                                          \
  }

    ISSUE(0);
    float4 gxv0 = *(const float4*)gxp;
    float4 gxv1 = *(const float4*)(gxp + 4);
    for (int t = 0; t < 512; ++t) {
      // prefetch NEXT step's gx now: latency hides under this step entirely,
      // and the spin's vmcnt(0) next iteration won't wait on a fresh HBM load
      float4 gxn0, gxn1;
      if (t + 1 < 512) {
        gxn0 = *(const float4*)(gxp + (size_t)(t + 1) * 4096);
        gxn1 = *(const float4*)(gxp + (size_t)(t + 1) * 4096 + 4);
      }
      SPINFIX(t);
      // partial GEMM: this wave's K-quarter, all 128 pcols, 16 batches
      f32x4 acc[8] = {};
#pragma unroll
      for (int kc = 0; kc < 8; ++kc) {
        const bf16x8 hf = mkfrag(hw[kc * 2], hw[kc * 2 + 1]);
#pragma unroll
        for (int j = 0; j < 8; ++j)
          acc[j] = mfma_bf16(hf, ldfrag(wbase + j * 16 * 1024 + kc * 32), acc[j]);
      }
      const int p = t & 1;
#pragma unroll
      for (int j = 0; j < 8; ++j)
#pragma unroll
        for (int ii = 0; ii < 4; ++ii)
          part[p][wave][lg * 4 + ii][j * 16 + lr] = acc[j][ii];
      __syncthreads();  // the ONLY barrier per step
      // gate phase: thread (gb, up) -> local units 2up, 2up+1
      float4 sA = *(const float4*)&part[p][0][gb][up * 8];
      float4 sB = *(const float4*)&part[p][0][gb][up * 8 + 4];
#pragma unroll
      for (int w = 1; w < 4; ++w) {
        const float4 a = *(const float4*)&part[p][w][gb][up * 8];
        const float4 b = *(const float4*)&part[p][w][gb][up * 8 + 4];
        sA.x += a.x; sA.y += a.y; sA.z += a.z; sA.w += a.w;
        sB.x += b.x; sB.y += b.y; sB.z += b.z; sB.w += b.w;
      }
      float hA, hB;
      {
        const float si = sA.x + gxv0.x, sj = sA.y + gxv0.y;
        const float sf_ = sA.z + gxv0.z, so = sA.w + gxv0.w;
        const float ig = 1.f / (1.f + __expf(-si));
        const float jg = 1.f - 2.f / (__expf(2.f * sj) + 1.f);
        const float fg = 1.f / (1.f + __expf(-sf_));
        const float og = 1.f / (1.f + __expf(-so));
        cs0 = fg * cs0 + ig * jg;
        hA = og * (1.f - 2.f / (__expf(2.f * cs0) + 1.f));
      }
      {
        const float si = sB.x + gxv1.x, sj = sB.y + gxv1.y;
        const float sf_ = sB.z + gxv1.z, so = sB.w + gxv1.w;
        const float ig = 1.f / (1.f + __expf(-si));
        const float jg = 1.f - 2.f / (__expf(2.f * sj) + 1.f);
        const float fg = 1.f / (1.f + __expf(-sf_));
        const float og = 1.f / (1.f + __expf(-so));
        cs1 = fg * cs1 + ig * jg;
        hB = og * (1.f - 2.f / (__expf(2.f * cs1) + 1.f));
      }
      const u32 myw = (u32)f2bf(hA) | ((u32)f2bf(hB) << 16);
      const u32 otherw = (u32)__shfl_down((int)myw, 1);
      if (!(up & 1)) {  // publish u64 covering local units 2up..2up+3
        u64 w64 = (u64)myw | ((u64)otherw << 32);
        u64* dst = (u64*)(hbuf + (size_t)(t + 1) * 16384 + (size_t)gb * 1024 +
                          g * 32 + up * 2);
        __hip_atomic_store(dst, w64, __ATOMIC_RELAXED, __HIP_MEMORY_SCOPE_AGENT);
      }
      ISSUE(t + 1);  // re-issue gather immediately after publish (hbuf[513] ok)
      gxv0 = gxn0;
      gxv1 = gxn1;
    }
#undef ISSUE
#undef SPINFIX
  } else {
    // ================= FFN1 worker branch =================
    // tiles idx = mi*32 + ni over [64 x 32]; worker wk takes idx = wk, +192...
    const int wk = g - SCAN_NW;
    u16* As = (u16*)&part[0][0][0][0];
    u16* Bs = As + 128 * 32;
    const int wr = (wave >> 1) * 64, wc = (wave & 1) * 64;
    for (int idx = wk; idx < 2048; idx += NWORK) {
      const int mi = idx >> 5, ni = idx & 31;
      const u16* Arows = hbuf + 16384 + (size_t)mi * 131072;  // 128 rows
      // wave0 sentinel-polls the tile's LAST timestep rows (rows 112..127;
      // monotone publication => all earlier rows visible in L3 too)
      if (wave == 0) {
        const u64* pr = (const u64*)(Arows + 112 * 1024) + (size_t)lane * 32;
        u64 v[32];
#pragma unroll
        for (int i = 0; i < 32; ++i) v[i] = aload(pr + i);
        int guard = 0;
        for (;;) {
          bool ok = true;
#pragma unroll
          for (int i = 0; i < 32; ++i) ok &= (v[i] != SENT);
          if (__all((int)ok)) break;
          __builtin_amdgcn_s_sleep(64);  // coarse cadence: no L3 poll storm
          if (++guard > (1 << 22)) break;
#pragma unroll
          for (int i = 0; i < 32; ++i)
            if (v[i] == SENT) v[i] = aload(pr + i);
        }
      }
      __syncthreads();  // release waves 1-3 after data ready
      // ---- standard 128x128x1024 tile: relu(h@W1 + b1) -> ffn1 ----
      f32x4 acc[4][4] = {};
      const int sr = lane >> 2, sce = (lane & 3) * 8;
      const u16* gA = Arows + (size_t)(wave * 16 + sr) * 1024 + sce;
      const u16* gB = w1t + (size_t)(ni * 128 + wave * 16 + sr) * 1024 + sce;
      u16* lA = As + wave * 16 * 32;
      u16* lB = Bs + wave * 16 * 32;
      for (int k0 = 0; k0 < 1024; k0 += 32) {
        __syncthreads();
        load_lds16(gA + k0, lA);
        load_lds16(gA + k0 + 64 * 1024, lA + 64 * 32);
        load_lds16(gB + k0, lB);
        load_lds16(gB + k0 + 64 * 1024, lB + 64 * 32);
        __syncthreads();
        bf16x8 af[4], bfr[4];
        const u16* pa = As + (wr + lr) * 32 + lg * 8;
        const u16* pb = Bs + (wc + lr) * 32 + lg * 8;
#pragma unroll
        for (int i = 0; i < 4; ++i) af[i] = ldfrag(pa + i * 16 * 32);
#pragma unroll
        for (int j = 0; j < 4; ++j) bfr[j] = ldfrag(pb + j * 16 * 32);
#pragma unroll
        for (int i = 0; i < 4; ++i)
#pragma unroll
          for (int j = 0; j < 4; ++j)
            acc[i][j] = mfma_bf16(af[i], bfr[j], acc[i][j]);
      }
      const int col0 = ni * 128 + wc + lr;
      const int row0 = mi * 128 + wr + lg * 4;
#pragma unroll
      for (int i = 0; i < 4; ++i) {
#pragma unroll
        for (int j = 0; j < 4; ++j) {
          const int c = col0 + j * 16;
          const float bv = b1f[c];
#pragma unroll
          for (int ii = 0; ii < 4; ++ii) {
            const int R = row0 + i * 16 + ii;
            const float v = fmaxf(acc[i][j][ii] + bv, 0.f);
            u16* ob = (R < 6144) ? (f0 + (size_t)R * 4096)
                                 : (f1 + (size_t)(R - 6144) * 4096);
            ob[c] = f2bf(v);
          }
        }
      }
      __syncthreads();  // As/Bs reuse safety before next tile's staging
    }
  }
}

// ---------------- host ----------------

extern "C" void kernel_launch(void* const* d_in, const int* in_sizes, int n_in,
                              void* d_out, int out_size, void* d_ws, size_t ws_size,
                              hipStream_t stream) {
  const float* x        = (const float*)d_in[0];
  const float* mem      = (const float*)d_in[1];
  const float* src_bias = (const float*)d_in[2];
  const float* w_src_q = (const float*)d_in[4];  const float* b_src_q = (const float*)d_in[5];
  const float* w_src_k = (const float*)d_in[6];  const float* b_src_k = (const float*)d_in[7];
  const float* w_src_v = (const float*)d_in[8];  const float* b_src_v = (const float*)d_in[9];
  const float* w_src_o = (const float*)d_in[10]; const float* b_src_o = (const float*)d_in[11];
  const float* w_tgt_q = (const float*)d_in[12]; const float* b_tgt_q = (const float*)d_in[13];
  const float* w_tgt_k = (const float*)d_in[14]; const float* b_tgt_k = (const float*)d_in[15];
  const float* w_tgt_v = (const float*)d_in[16]; const float* b_tgt_v = (const float*)d_in[17];
  const float* w_tgt_o = (const float*)d_in[18]; const float* b_tgt_o = (const float*)d_in[19];
  const float* lstm_w  = (const float*)d_in[20]; const float* lstm_b  = (const float*)d_in[21];
  const float* w1 = (const float*)d_in[22]; const float* b1f = (const float*)d_in[23];
  const float* w2 = (const float*)d_in[24]; const float* b2f = (const float*)d_in[25];

  char* ws = (char*)d_ws;
  const size_t MiB = 1024ull * 1024ull;
  u16*   xcb  = (u16*)(ws + 0);             // [8192][2048] (dead at scan time)
  u16*   wlp  = (u16*)(ws + 32 * MiB);      // (dead at scan time)
  u16*   whp  = (u16*)(ws + 48 * MiB);
  u16*   w1t  = (u16*)(ws + 56 * MiB);
  u16*   w2t  = (u16*)(ws + 64 * MiB);
  float* pb   = (float*)(ws + 72 * MiB);
  u16*   hbuf = (u16*)(ws + 73 * MiB);      // [513][16][1024]
  u16*   memb = (u16*)(ws + 90 * MiB);
  u16*   wt[8];
  for (int i = 0; i < 8; ++i) wt[i] = (u16*)(ws + 106 * MiB + (size_t)i * 2 * MiB);
  u16*   bq   = (u16*)(ws + 122 * MiB);
  u16*   bk   = (u16*)(ws + 138 * MiB);
  u16*   bv   = (u16*)(ws + 154 * MiB);
  u16*   ao_s = (u16*)(ws + 170 * MiB);
  u16*   ao_t = (u16*)(ws + 186 * MiB);
  float* c32  = (float*)(ws + 202 * MiB);   // ..234 (dead at scan time)
  float* gx   = (float*)(ws + 90 * MiB);    // overlay 90..218 (live during scan)
  u16*   f0   = (u16*)(ws + 0);             // ffn1 rows 0..6143   (48 MiB)
  u16*   f1   = (u16*)(ws + 218 * MiB);     // ffn1 rows 6144..8191 (16 MiB)

  // sentinel-fill h rows 1..512 FIRST (dirty memset lines written back by the
  // ~1ms of GEMM traffic before the scan; scan polls via L2-bypass)
  hipMemsetAsync(hbuf + 16384, 0xFF, (size_t)512 * 16384 * 2, stream);
  hipMemsetAsync(hbuf, 0, 32768, stream);   // h_0 = 0

  // --- conversions ---
  cvt_x_kernel<<<8192, 256, 0, stream>>>(xcb, x);
  cvt_bf16_kernel<<<8192, 256, 0, stream>>>(memb, mem, 2097152);
  const dim3 g1k(32, 32);
  convt_kernel<<<g1k, 256, 0, stream>>>(wt[0], w_src_q, 1024, 1024, 0, 0.125f);
  convt_kernel<<<g1k, 256, 0, stream>>>(wt[1], w_src_k, 1024, 1024, 0, 1.f);
  convt_kernel<<<g1k, 256, 0, stream>>>(wt[2], w_src_v, 1024, 1024, 0, 1.f);
  convt_kernel<<<g1k, 256, 0, stream>>>(wt[3], w_src_o, 1024, 1024, 0, 1.f);
  convt_kernel<<<g1k, 256, 0, stream>>>(wt[4], w_tgt_q, 1024, 1024, 0, 0.125f);
  convt_kernel<<<g1k, 256, 0, stream>>>(wt[5], w_tgt_k, 1024, 1024, 0, 1.f);
  convt_kernel<<<g1k, 256, 0, stream>>>(wt[6], w_tgt_v, 1024, 1024, 0, 1.f);
  convt_kernel<<<g1k, 256, 0, stream>>>(wt[7], w_tgt_o, 1024, 1024, 0, 1.f);
  convt_perm_kernel<<<dim3(32, 64, 4), 256, 0, stream>>>(wlp, lstm_w, 2048, 0);
  convt_perm_kernel<<<dim3(32, 32, 4), 256, 0, stream>>>(whp, lstm_w, 1024, 2048);
  convt_kernel<<<dim3(128, 32), 256, 0, stream>>>(w1t, w1, 1024, 4096, 0, 1.f);
  convt_kernel<<<dim3(32, 128), 256, 0, stream>>>(w2t, w2, 4096, 1024, 0, 1.f);
  pack_bias_kernel<<<16, 256, 0, stream>>>(pb, lstm_b);

  const dim3 gN1(8, 64);   // N=1024
  const dim3 gN4(32, 64);  // N=4096

  // --- src attention ---
  gemm_bt_kernel<1, 0, 0, 0><<<gN1, 256, 0, stream>>>(xcb, 2048, wt[0], b_src_q, 0.125f, bq, 1024, nullptr, 0, 1024, 0);
  gemm_bt_kernel<1, 0, 0, 0><<<gN1, 256, 0, stream>>>(memb, 1024, wt[1], b_src_k, 1.f, bk, 1024, nullptr, 0, 1024, 0);
  gemm_bt_kernel<1, 0, 0, 0><<<gN1, 256, 0, stream>>>(memb, 1024, wt[2], b_src_v, 1.f, bv, 1024, nullptr, 0, 1024, 0);
  flash_kernel<0><<<dim3(8, 16, 16), 256, 0, stream>>>(bq, bk, bv, src_bias, ao_s);
  // --- tgt (causal self) attention ---
  gemm_bt_kernel<1, 0, 0, 0><<<gN1, 256, 0, stream>>>(xcb, 2048, wt[4], b_tgt_q, 0.125f, bq, 1024, nullptr, 0, 1024, 0);
  gemm_bt_kernel<1, 0, 0, 0><<<gN1, 256, 0, stream>>>(xcb, 2048, wt[5], b_tgt_k, 1.f, bk, 1024, nullptr, 0, 1024, 0);
  gemm_bt_kernel<1, 0, 0, 0><<<gN1, 256, 0, stream>>>(xcb, 2048, wt[6], b_tgt_v, 1.f, bv, 1024, nullptr, 0, 1024, 0);
  flash_kernel<1><<<dim3(8, 16, 16), 256, 0, stream>>>(bq, bk, bv, nullptr, ao_t);
  // --- c = ao_s@Wo_s + bo_s + ao_t@Wo_t + bo_t -> xcb cols 1024+ ---
  gemm_bt_kernel<0, 0, 0, 0><<<gN1, 256, 0, stream>>>(ao_s, 1024, wt[3], b_src_o, 1.f, c32, 1024, nullptr, 0, 1024, 0);
  gemm_bt_kernel<1, 1, 0, 0><<<gN1, 256, 0, stream>>>(ao_t, 1024, wt[7], b_tgt_o, 1.f, xcb + 1024, 2048, c32, 1024, 1024, 0);
  // --- gx = [x|c] @ wlp^T + pb  (K=2048, packed cols) ---
  gemm_bt_kernel<0, 0, 0, 0><<<gN4, 256, 0, stream>>>(xcb, 2048, wlp, pb, 1.f, gx, 4096, nullptr, 0, 2048, 0);
  // --- fused LSTM scan (32 WGs) + FFN1 workers (192 WGs); 80KB LDS -> 1 WG/CU
  lstm_scan_kernel<<<dim3(SCAN_NW + NWORK), 256, 14336, stream>>>(
      whp, gx, hbuf, w1t, b1f, f0, f1);
  // --- FFN2 (two launches over the split ffn1 regions) ---
  gemm_bt_kernel<0, 0, 0, 2><<<dim3(8, 48), 256, 0, stream>>>(f0, 4096, w2t, b2f, 1.f, (float*)d_out, 1024, nullptr, 0, 4096, 0);
  gemm_bt_kernel<0, 0, 0, 2><<<dim3(8, 16), 256, 0, stream>>>(f1, 4096, w2t, b2f, 1.f, (float*)d_out, 1024, nullptr, 0, 4096, 6144);
}